// Round 1
// baseline (295.536 us; speedup 1.0000x reference)
//
#include <hip/hip_runtime.h>

#define NB 8
#define NN 8192
#define LAT 64
#define IN2 128
#define NSTEPS 4
#define REPS 3

#define NI 64      // interfaces per block
#define NROWS 63   // z rows updated per block
#define XP 136     // X pitch in bf16 elems (128 + 8 pad) -> 272B rows, 16B aligned
#define HP 72      // H pitch (64 + 8)
#define FP 68      // flux pitch in f32 (same 272B rows, overlays X)

typedef __attribute__((ext_vector_type(8))) short bf16x8;
typedef __attribute__((ext_vector_type(4))) float f32x4;

__device__ __forceinline__ unsigned short f2bf(float f) {
    union { float f; unsigned u; } v; v.f = f;
    unsigned r = v.u + 0x7FFFu + ((v.u >> 16) & 1u);  // RNE
    return (unsigned short)(r >> 16);
}

__device__ __forceinline__ float gelu_exact(float x) {
    return 0.5f * x * (1.0f + erff(x * 0.70710678118654752440f));
}

__global__ void encode_kernel(const float* __restrict__ u0,
                              const float* __restrict__ w_enc,
                              float* __restrict__ z,
                              float* __restrict__ out) {
    int t = threadIdx.x;
    int g = t & 3;
    int r = t >> 2;
    long row = (long)blockIdx.x * 64 + r;   // b*NN + n
    float u = u0[row];
    const float4* w4p = (const float4*)w_enc;
    float4 w4[4];
#pragma unroll
    for (int j = 0; j < 4; ++j) w4[j] = w4p[g * 4 + j];
    float4* zp = (float4*)(z + row * 64 + g * 16);
#pragma unroll
    for (int j = 0; j < 4; ++j) {
        float4 o;
        o.x = u * w4[j].x; o.y = u * w4[j].y; o.z = u * w4[j].z; o.w = u * w4[j].w;
        zp[j] = o;
    }
    if (g == 0) {
        float s2 = 0.f;
#pragma unroll
        for (int j = 0; j < 16; ++j) {
            float4 w = w4p[j];
            s2 += w.x * w.x + w.y * w.y + w.z * w.z + w.w * w.w;
        }
        int b = (int)(row >> 13);
        int n = (int)(row & (NN - 1));
        out[((long)b * NSTEPS) * NN + n] = u * (s2 / (s2 + 1e-8f));
    }
}

__global__ void decode_kernel(const float* __restrict__ z,
                              const float* __restrict__ w_enc,
                              float* __restrict__ out, int step) {
    int t = threadIdx.x;
    int g = t & 3;
    int r = t >> 2;
    long row = (long)blockIdx.x * 64 + r;
    const float4* w4p = (const float4*)w_enc;
    const float4* z4p = (const float4*)(z + row * 64 + g * 16);
    float dot = 0.f, w2 = 0.f;
#pragma unroll
    for (int j = 0; j < 4; ++j) {
        float4 w = w4p[g * 4 + j];
        float4 zv = z4p[j];
        dot += zv.x * w.x + zv.y * w.y + zv.z * w.z + zv.w * w.w;
        w2 += w.x * w.x + w.y * w.y + w.z * w.z + w.w * w.w;
    }
    dot += __shfl_xor(dot, 1);
    dot += __shfl_xor(dot, 2);
    w2 += __shfl_xor(w2, 1);
    w2 += __shfl_xor(w2, 2);
    if (g == 0) {
        int b = (int)(row >> 13);
        int n = (int)(row & (NN - 1));
        out[((long)b * NSTEPS + step) * NN + n] = dot / (w2 + 1e-8f);
    }
}

__global__ __launch_bounds__(256, 2)
void substep_kernel(const float* __restrict__ zin,
                    float* __restrict__ zout,
                    const float* __restrict__ W1, const float* __restrict__ b1,
                    const float* __restrict__ W2, const float* __restrict__ b2,
                    const float* __restrict__ W3, const float* __restrict__ b3,
                    const float* __restrict__ dtp, const float* __restrict__ dxp) {
    __shared__ unsigned short Xs[NI * XP];     // sym features, later flux (f32) overlay
    __shared__ unsigned short H1s[NI * HP];
    __shared__ unsigned short H2s[NI * HP];
    __shared__ unsigned short W1t[LAT * XP];   // W1^T: [j][k], k<128
    __shared__ unsigned short W2t[LAT * HP];
    __shared__ unsigned short W3t[LAT * HP];
    __shared__ float b1s[LAT], b2s[LAT], b3s[LAT];
    float* fluxS = (float*)Xs;                 // [NI][FP]

    int t = threadIdx.x;
    int chunk = blockIdx.x;
    int b = blockIdx.y;
    int i0 = chunk * NROWS;                    // global interface base

    // ---- stage weights (transposed, bf16) ----
    for (int idx = t; idx < IN2 * LAT; idx += 256) {
        int k = idx >> 6, j = idx & 63;
        W1t[j * XP + k] = f2bf(W1[idx]);
    }
    for (int idx = t; idx < LAT * LAT; idx += 256) {
        int k = idx >> 6, j = idx & 63;
        W2t[j * HP + k] = f2bf(W2[idx]);
        W3t[j * HP + k] = f2bf(W3[idx]);
    }
    if (t < LAT) { b1s[t] = b1[t]; b2s[t] = b2[t]; b3s[t] = b3[t]; }

    // ---- build sym features X[r][0:64]=zl+zr, X[r][64:128]=|zl-zr| ----
    {
        int g = t & 3, r = t >> 2;
        int i = i0 + r;
        int nl = i - 1; if (nl < 0) nl = 0; if (nl > NN - 1) nl = NN - 1;
        int nr = i; if (nr > NN - 1) nr = NN - 1;
        const float4* zl = (const float4*)(zin + ((long)b * NN + nl) * 64 + g * 16);
        const float4* zr = (const float4*)(zin + ((long)b * NN + nr) * 64 + g * 16);
        union { unsigned short s[16]; int4 v[2]; } vs, va;
#pragma unroll
        for (int j = 0; j < 4; ++j) {
            float4 a = zl[j], c = zr[j];
            vs.s[j * 4 + 0] = f2bf(a.x + c.x);
            vs.s[j * 4 + 1] = f2bf(a.y + c.y);
            vs.s[j * 4 + 2] = f2bf(a.z + c.z);
            vs.s[j * 4 + 3] = f2bf(a.w + c.w);
            va.s[j * 4 + 0] = f2bf(fabsf(a.x - c.x));
            va.s[j * 4 + 1] = f2bf(fabsf(a.y - c.y));
            va.s[j * 4 + 2] = f2bf(fabsf(a.z - c.z));
            va.s[j * 4 + 3] = f2bf(fabsf(a.w - c.w));
        }
        int4* xs = (int4*)&Xs[r * XP + g * 16];
        int4* xa = (int4*)&Xs[r * XP + 64 + g * 16];
        xs[0] = vs.v[0]; xs[1] = vs.v[1];
        xa[0] = va.v[0]; xa[1] = va.v[1];
    }
    __syncthreads();

    int lane = t & 63;
    int wv = t >> 6;
    int arow = lane & 15;
    int apart = lane >> 4;
    int rbase = wv * 16;

    // ---- layer 1: [16,128] @ [128,64] ----
    {
        f32x4 acc[4];
#pragma unroll
        for (int ct = 0; ct < 4; ++ct) acc[ct] = (f32x4){0.f, 0.f, 0.f, 0.f};
        bf16x8 a[4];
#pragma unroll
        for (int kt = 0; kt < 4; ++kt)
            a[kt] = *(const bf16x8*)&Xs[(rbase + arow) * XP + kt * 32 + apart * 8];
#pragma unroll
        for (int ct = 0; ct < 4; ++ct) {
#pragma unroll
            for (int kt = 0; kt < 4; ++kt) {
                bf16x8 bf = *(const bf16x8*)&W1t[(ct * 16 + arow) * XP + kt * 32 + apart * 8];
                acc[ct] = __builtin_amdgcn_mfma_f32_16x16x32_bf16(a[kt], bf, acc[ct], 0, 0, 0);
            }
        }
#pragma unroll
        for (int ct = 0; ct < 4; ++ct) {
            int col = ct * 16 + arow;
            float bb = b1s[col];
#pragma unroll
            for (int r = 0; r < 4; ++r) {
                float h = gelu_exact(acc[ct][r] + bb);
                H1s[(rbase + apart * 4 + r) * HP + col] = f2bf(h);
            }
        }
    }
    __syncthreads();

    // ---- layer 2: [16,64] @ [64,64] ----
    {
        f32x4 acc[4];
#pragma unroll
        for (int ct = 0; ct < 4; ++ct) acc[ct] = (f32x4){0.f, 0.f, 0.f, 0.f};
        bf16x8 a[2];
#pragma unroll
        for (int kt = 0; kt < 2; ++kt)
            a[kt] = *(const bf16x8*)&H1s[(rbase + arow) * HP + kt * 32 + apart * 8];
#pragma unroll
        for (int ct = 0; ct < 4; ++ct) {
#pragma unroll
            for (int kt = 0; kt < 2; ++kt) {
                bf16x8 bf = *(const bf16x8*)&W2t[(ct * 16 + arow) * HP + kt * 32 + apart * 8];
                acc[ct] = __builtin_amdgcn_mfma_f32_16x16x32_bf16(a[kt], bf, acc[ct], 0, 0, 0);
            }
        }
#pragma unroll
        for (int ct = 0; ct < 4; ++ct) {
            int col = ct * 16 + arow;
            float bb = b2s[col];
#pragma unroll
            for (int r = 0; r < 4; ++r) {
                float h = gelu_exact(acc[ct][r] + bb);
                H2s[(rbase + apart * 4 + r) * HP + col] = f2bf(h);
            }
        }
    }
    __syncthreads();

    // ---- layer 3 + tanh*0.25 -> flux (overlays Xs) ----
    {
        f32x4 acc[4];
#pragma unroll
        for (int ct = 0; ct < 4; ++ct) acc[ct] = (f32x4){0.f, 0.f, 0.f, 0.f};
        bf16x8 a[2];
#pragma unroll
        for (int kt = 0; kt < 2; ++kt)
            a[kt] = *(const bf16x8*)&H2s[(rbase + arow) * HP + kt * 32 + apart * 8];
#pragma unroll
        for (int ct = 0; ct < 4; ++ct) {
#pragma unroll
            for (int kt = 0; kt < 2; ++kt) {
                bf16x8 bf = *(const bf16x8*)&W3t[(ct * 16 + arow) * HP + kt * 32 + apart * 8];
                acc[ct] = __builtin_amdgcn_mfma_f32_16x16x32_bf16(a[kt], bf, acc[ct], 0, 0, 0);
            }
        }
#pragma unroll
        for (int ct = 0; ct < 4; ++ct) {
            int col = ct * 16 + arow;
            float bb = b3s[col];
#pragma unroll
            for (int r = 0; r < 4; ++r) {
                float f = tanhf(acc[ct][r] + bb) * 0.25f;
                fluxS[(rbase + apart * 4 + r) * FP + col] = f;
            }
        }
    }
    __syncthreads();

    // ---- z update: z[n] -= c*(flux[r+1]-flux[r]) ----
    {
        int g = t & 3, r = t >> 2;
        int n = i0 + r;
        if (r < NROWS && n < NN) {
            float c = (dtp[0] / (float)REPS) / dxp[0];
            const float4* zi = (const float4*)(zin + ((long)b * NN + n) * 64 + g * 16);
            float4* zo = (float4*)(zout + ((long)b * NN + n) * 64 + g * 16);
            const float4* fhi = (const float4*)&fluxS[(r + 1) * FP + g * 16];
            const float4* flo = (const float4*)&fluxS[r * FP + g * 16];
#pragma unroll
            for (int j = 0; j < 4; ++j) {
                float4 zv = zi[j];
                float4 h = fhi[j], l = flo[j];
                float4 o;
                o.x = zv.x - c * (h.x - l.x);
                o.y = zv.y - c * (h.y - l.y);
                o.z = zv.z - c * (h.z - l.z);
                o.w = zv.w - c * (h.w - l.w);
                zo[j] = o;
            }
        }
    }
}

extern "C" void kernel_launch(void* const* d_in, const int* in_sizes, int n_in,
                              void* d_out, int out_size, void* d_ws, size_t ws_size,
                              hipStream_t stream) {
    const float* u0 = (const float*)d_in[0];
    const float* w_enc = (const float*)d_in[1];
    const float* W1 = (const float*)d_in[2];
    const float* b1 = (const float*)d_in[3];
    const float* W2 = (const float*)d_in[4];
    const float* b2 = (const float*)d_in[5];
    const float* W3 = (const float*)d_in[6];
    const float* b3 = (const float*)d_in[7];
    const float* dt = (const float*)d_in[8];
    const float* dx = (const float*)d_in[9];
    float* out = (float*)d_out;

    float* z0 = (float*)d_ws;
    float* z1 = z0 + (size_t)NB * NN * LAT;

    encode_kernel<<<dim3(NB * NN / 64), 256, 0, stream>>>(u0, w_enc, z0, out);

    float* cur = z0;
    float* nxt = z1;
    int chunks = (NN + NROWS - 1) / NROWS;  // 131
    for (int s = 1; s < NSTEPS; ++s) {
        for (int rep = 0; rep < REPS; ++rep) {
            substep_kernel<<<dim3(chunks, NB), 256, 0, stream>>>(
                cur, nxt, W1, b1, W2, b2, W3, b3, dt, dx);
            float* tmp = cur; cur = nxt; nxt = tmp;
        }
        decode_kernel<<<dim3(NB * NN / 64), 256, 0, stream>>>(cur, w_enc, out, s);
    }
}

// Round 2
// 197.383 us; speedup vs baseline: 1.4973x; 1.4973x over previous
//
#include <hip/hip_runtime.h>

#define NB 8
#define NN 8192
#define LAT 64
#define IN2 128
#define NSTEPS 4
#define REPS 3

#define NI 64      // interfaces per block
#define NROWS 63   // z rows updated per block
#define XP 136     // X pitch in bf16 elems (128 + 8 pad) -> 272B rows
#define HP 72      // H pitch in bf16 elems (64 + 8) -> 144B rows
#define FP 68      // flux pitch in f32 (272B rows, overlays X)

typedef __attribute__((ext_vector_type(8))) short bf16x8;
typedef __attribute__((ext_vector_type(4))) float f32x4;

__device__ __forceinline__ unsigned short f2bf(float f) {
    union { float f; unsigned u; } v; v.f = f;
    unsigned r = v.u + 0x7FFFu + ((v.u >> 16) & 1u);  // RNE
    return (unsigned short)(r >> 16);
}

// tanh(x) = 1 - 2/(exp(2x)+1)  (exp-based, saturates correctly at +-inf)
__device__ __forceinline__ float tanh_fast(float x) {
    return 1.0f - 2.0f / (__expf(2.0f * x) + 1.0f);
}

// tanh-approx GELU (max abs err ~1e-3)
__device__ __forceinline__ float gelu_fast(float x) {
    float t = tanh_fast(0.7978845608028654f * (x + 0.044715f * x * x * x));
    return 0.5f * x * (1.0f + t);
}

__global__ void encode_kernel(const float* __restrict__ u0,
                              const float* __restrict__ w_enc,
                              float* __restrict__ z,
                              float* __restrict__ out) {
    int t = threadIdx.x;
    int g = t & 3;
    int r = t >> 2;
    long row = (long)blockIdx.x * 64 + r;   // b*NN + n
    float u = u0[row];
    const float4* w4p = (const float4*)w_enc;
    float4 w4[4];
#pragma unroll
    for (int j = 0; j < 4; ++j) w4[j] = w4p[g * 4 + j];
    float4* zp = (float4*)(z + row * 64 + g * 16);
#pragma unroll
    for (int j = 0; j < 4; ++j) {
        float4 o;
        o.x = u * w4[j].x; o.y = u * w4[j].y; o.z = u * w4[j].z; o.w = u * w4[j].w;
        zp[j] = o;
    }
    if (g == 0) {
        float s2 = 0.f;
#pragma unroll
        for (int j = 0; j < 16; ++j) {
            float4 w = w4p[j];
            s2 += w.x * w.x + w.y * w.y + w.z * w.z + w.w * w.w;
        }
        int b = (int)(row >> 13);
        int n = (int)(row & (NN - 1));
        out[((long)b * NSTEPS) * NN + n] = u * (s2 / (s2 + 1e-8f));
    }
}

__global__ void decode_kernel(const float* __restrict__ z,
                              const float* __restrict__ w_enc,
                              float* __restrict__ out, int step) {
    int t = threadIdx.x;
    int g = t & 3;
    int r = t >> 2;
    long row = (long)blockIdx.x * 64 + r;
    const float4* w4p = (const float4*)w_enc;
    const float4* z4p = (const float4*)(z + row * 64 + g * 16);
    float dot = 0.f, w2 = 0.f;
#pragma unroll
    for (int j = 0; j < 4; ++j) {
        float4 w = w4p[g * 4 + j];
        float4 zv = z4p[j];
        dot += zv.x * w.x + zv.y * w.y + zv.z * w.z + zv.w * w.w;
        w2 += w.x * w.x + w.y * w.y + w.z * w.z + w.w * w.w;
    }
    dot += __shfl_xor(dot, 1);
    dot += __shfl_xor(dot, 2);
    w2 += __shfl_xor(w2, 1);
    w2 += __shfl_xor(w2, 2);
    if (g == 0) {
        int b = (int)(row >> 13);
        int n = (int)(row & (NN - 1));
        out[((long)b * NSTEPS + step) * NN + n] = dot / (w2 + 1e-8f);
    }
}

__global__ __launch_bounds__(256, 4)
void substep_kernel(const float* __restrict__ zin,
                    float* __restrict__ zout,
                    const float* __restrict__ W1, const float* __restrict__ b1,
                    const float* __restrict__ W2, const float* __restrict__ b2,
                    const float* __restrict__ W3, const float* __restrict__ b3,
                    const float* __restrict__ dtp, const float* __restrict__ dxp) {
    __shared__ unsigned short Xs[NI * XP];     // sym features; flux (f32) overlays later
    __shared__ unsigned short H1s[NI * HP];
    __shared__ unsigned short H2s[NI * HP];
    float* fluxS = (float*)Xs;                 // [NI][FP]

    int t = threadIdx.x;
    int chunk = blockIdx.x;
    int b = blockIdx.y;
    int i0 = chunk * NROWS;                    // global interface base

    int lane = t & 63;
    int wv = t >> 6;          // wave id == output column tile ct
    int arow = lane & 15;
    int apart = lane >> 4;
    int col = wv * 16 + arow; // this lane's output column (B-frag col)

    // ---- per-wave weight fragments in registers (one-time L2-cached gather) ----
    bf16x8 w1f[4], w2f[2], w3f[2];
#pragma unroll
    for (int kt = 0; kt < 4; ++kt) {
        bf16x8 w;
#pragma unroll
        for (int e = 0; e < 8; ++e) {
            int k = kt * 32 + apart * 8 + e;
            w[e] = (short)f2bf(W1[k * 64 + col]);
        }
        w1f[kt] = w;
    }
#pragma unroll
    for (int kt = 0; kt < 2; ++kt) {
        bf16x8 wa, wb;
#pragma unroll
        for (int e = 0; e < 8; ++e) {
            int k = kt * 32 + apart * 8 + e;
            wa[e] = (short)f2bf(W2[k * 64 + col]);
            wb[e] = (short)f2bf(W3[k * 64 + col]);
        }
        w2f[kt] = wa;
        w3f[kt] = wb;
    }
    float bb1 = b1[col], bb2 = b2[col], bb3 = b3[col];
    float c = (dtp[0] / (float)REPS) / dxp[0];

    // ---- build sym features X[r][0:64]=zl+zr, X[r][64:128]=|zl-zr| ----
    {
        int g = t & 3, r = t >> 2;
        int i = i0 + r;
        int nl = i - 1; if (nl < 0) nl = 0; if (nl > NN - 1) nl = NN - 1;
        int nr = i; if (nr > NN - 1) nr = NN - 1;
        const float4* zl = (const float4*)(zin + ((long)b * NN + nl) * 64 + g * 16);
        const float4* zr = (const float4*)(zin + ((long)b * NN + nr) * 64 + g * 16);
        union { unsigned short s[16]; int4 v[2]; } vs, va;
#pragma unroll
        for (int j = 0; j < 4; ++j) {
            float4 a = zl[j], cc = zr[j];
            vs.s[j * 4 + 0] = f2bf(a.x + cc.x);
            vs.s[j * 4 + 1] = f2bf(a.y + cc.y);
            vs.s[j * 4 + 2] = f2bf(a.z + cc.z);
            vs.s[j * 4 + 3] = f2bf(a.w + cc.w);
            va.s[j * 4 + 0] = f2bf(fabsf(a.x - cc.x));
            va.s[j * 4 + 1] = f2bf(fabsf(a.y - cc.y));
            va.s[j * 4 + 2] = f2bf(fabsf(a.z - cc.z));
            va.s[j * 4 + 3] = f2bf(fabsf(a.w - cc.w));
        }
        int4* xs = (int4*)&Xs[r * XP + g * 16];
        int4* xa = (int4*)&Xs[r * XP + 64 + g * 16];
        xs[0] = vs.v[0]; xs[1] = vs.v[1];
        xa[0] = va.v[0]; xa[1] = va.v[1];
    }
    __syncthreads();

    // ---- layer 1: rows 64 x k 128 -> this wave's 16 cols ----
#pragma unroll
    for (int rt = 0; rt < 4; ++rt) {
        f32x4 acc = (f32x4){0.f, 0.f, 0.f, 0.f};
#pragma unroll
        for (int kt = 0; kt < 4; ++kt) {
            bf16x8 a = *(const bf16x8*)&Xs[(rt * 16 + arow) * XP + kt * 32 + apart * 8];
            acc = __builtin_amdgcn_mfma_f32_16x16x32_bf16(a, w1f[kt], acc, 0, 0, 0);
        }
#pragma unroll
        for (int r = 0; r < 4; ++r) {
            float h = gelu_fast(acc[r] + bb1);
            H1s[(rt * 16 + apart * 4 + r) * HP + col] = f2bf(h);
        }
    }
    __syncthreads();

    // ---- layer 2 ----
#pragma unroll
    for (int rt = 0; rt < 4; ++rt) {
        f32x4 acc = (f32x4){0.f, 0.f, 0.f, 0.f};
#pragma unroll
        for (int kt = 0; kt < 2; ++kt) {
            bf16x8 a = *(const bf16x8*)&H1s[(rt * 16 + arow) * HP + kt * 32 + apart * 8];
            acc = __builtin_amdgcn_mfma_f32_16x16x32_bf16(a, w2f[kt], acc, 0, 0, 0);
        }
#pragma unroll
        for (int r = 0; r < 4; ++r) {
            float h = gelu_fast(acc[r] + bb2);
            H2s[(rt * 16 + apart * 4 + r) * HP + col] = f2bf(h);
        }
    }
    __syncthreads();

    // ---- layer 3 + tanh*0.25 -> flux (overlays Xs) ----
#pragma unroll
    for (int rt = 0; rt < 4; ++rt) {
        f32x4 acc = (f32x4){0.f, 0.f, 0.f, 0.f};
#pragma unroll
        for (int kt = 0; kt < 2; ++kt) {
            bf16x8 a = *(const bf16x8*)&H2s[(rt * 16 + arow) * HP + kt * 32 + apart * 8];
            acc = __builtin_amdgcn_mfma_f32_16x16x32_bf16(a, w3f[kt], acc, 0, 0, 0);
        }
#pragma unroll
        for (int r = 0; r < 4; ++r) {
            float f = tanh_fast(acc[r] + bb3) * 0.25f;
            fluxS[(rt * 16 + apart * 4 + r) * FP + col] = f;
        }
    }
    __syncthreads();

    // ---- z update: z[n] -= c*(flux[r+1]-flux[r]) ----
    {
        int g = t & 3, r = t >> 2;
        int n = i0 + r;
        if (r < NROWS && n < NN) {
            const float4* zi = (const float4*)(zin + ((long)b * NN + n) * 64 + g * 16);
            float4* zo = (float4*)(zout + ((long)b * NN + n) * 64 + g * 16);
            const float4* fhi = (const float4*)&fluxS[(r + 1) * FP + g * 16];
            const float4* flo = (const float4*)&fluxS[r * FP + g * 16];
#pragma unroll
            for (int j = 0; j < 4; ++j) {
                float4 zv = zi[j];
                float4 h = fhi[j], l = flo[j];
                float4 o;
                o.x = zv.x - c * (h.x - l.x);
                o.y = zv.y - c * (h.y - l.y);
                o.z = zv.z - c * (h.z - l.z);
                o.w = zv.w - c * (h.w - l.w);
                zo[j] = o;
            }
        }
    }
}

extern "C" void kernel_launch(void* const* d_in, const int* in_sizes, int n_in,
                              void* d_out, int out_size, void* d_ws, size_t ws_size,
                              hipStream_t stream) {
    const float* u0 = (const float*)d_in[0];
    const float* w_enc = (const float*)d_in[1];
    const float* W1 = (const float*)d_in[2];
    const float* b1 = (const float*)d_in[3];
    const float* W2 = (const float*)d_in[4];
    const float* b2 = (const float*)d_in[5];
    const float* W3 = (const float*)d_in[6];
    const float* b3 = (const float*)d_in[7];
    const float* dt = (const float*)d_in[8];
    const float* dx = (const float*)d_in[9];
    float* out = (float*)d_out;

    float* z0 = (float*)d_ws;
    float* z1 = z0 + (size_t)NB * NN * LAT;

    encode_kernel<<<dim3(NB * NN / 64), 256, 0, stream>>>(u0, w_enc, z0, out);

    float* cur = z0;
    float* nxt = z1;
    int chunks = (NN + NROWS - 1) / NROWS;  // 131
    for (int s = 1; s < NSTEPS; ++s) {
        for (int rep = 0; rep < REPS; ++rep) {
            substep_kernel<<<dim3(chunks, NB), 256, 0, stream>>>(
                cur, nxt, W1, b1, W2, b2, W3, b3, dt, dx);
            float* tmp = cur; cur = nxt; nxt = tmp;
        }
        decode_kernel<<<dim3(NB * NN / 64), 256, 0, stream>>>(cur, w_enc, out, s);
    }
}

// Round 3
// 135.956 us; speedup vs baseline: 2.1738x; 1.4518x over previous
//
#include <hip/hip_runtime.h>

#define NB 8
#define NN 8192
#define LAT 64
#define NSTEPS 4
#define REPS 3

#define R_OUT 58            // output z rows per block
#define TROWS 64            // tile rows = R_OUT + 6 (halo 3 each side)
#define CHUNKS 142          // ceil(8192/58)
#define ZP 68               // z tile pitch (f32) -> 272B rows, balanced banks
#define XP 136              // X pitch (bf16) -> 272B rows
#define HP 72               // H pitch (bf16) -> 144B rows
#define FP 68               // flux pitch (f32), overlays Xs

typedef __attribute__((ext_vector_type(8))) short bf16x8;
typedef __attribute__((ext_vector_type(4))) float f32x4;

__device__ __forceinline__ unsigned short f2bf(float f) {
    union { float f; unsigned u; } v; v.f = f;
    unsigned r = v.u + 0x7FFFu + ((v.u >> 16) & 1u);  // RNE
    return (unsigned short)(r >> 16);
}

__device__ __forceinline__ float tanh_fast(float x) {
    return 1.0f - 2.0f / (__expf(2.0f * x) + 1.0f);
}

__device__ __forceinline__ float gelu_fast(float x) {
    float t = tanh_fast(0.7978845608028654f * (x + 0.044715f * x * x * x));
    return 0.5f * x * (1.0f + t);
}

__device__ __forceinline__ int iclamp(int v, int lo, int hi) {
    return v < lo ? lo : (v > hi ? hi : v);
}

template<bool FIRST, bool WRITE_Z>
__global__ __launch_bounds__(256, 3)
void step_kernel(const float* __restrict__ zin,   // u0 when FIRST
                 float* __restrict__ zout,
                 float* __restrict__ out,
                 int step,
                 const float* __restrict__ w_enc,
                 const float* __restrict__ W1, const float* __restrict__ b1,
                 const float* __restrict__ W2, const float* __restrict__ b2,
                 const float* __restrict__ W3, const float* __restrict__ b3,
                 const float* __restrict__ dtp, const float* __restrict__ dxp) {
    __shared__ float zt[TROWS * ZP];           // z tile, f32
    __shared__ unsigned short Xs[TROWS * XP];  // sym features; flux overlays
    __shared__ unsigned short H1s[TROWS * HP];
    __shared__ unsigned short H2s[TROWS * HP];
    float* fluxS = (float*)Xs;                 // [TROWS][FP]

    int t = threadIdx.x;
    int chunk = blockIdx.x;
    int b = blockIdx.y;
    int n0 = chunk * R_OUT;

    int lane = t & 63;
    int wv = t >> 6;           // wave id == output column tile
    int arow = lane & 15;
    int apart = lane >> 4;
    int col = wv * 16 + arow;  // this lane's MLP output column

    // ---- per-wave weight fragments (registers, L2-cached gather) ----
    bf16x8 w1f[4], w2f[2], w3f[2];
#pragma unroll
    for (int kt = 0; kt < 4; ++kt) {
        bf16x8 w;
#pragma unroll
        for (int e = 0; e < 8; ++e) {
            int k = kt * 32 + apart * 8 + e;
            w[e] = (short)f2bf(W1[k * 64 + col]);
        }
        w1f[kt] = w;
    }
#pragma unroll
    for (int kt = 0; kt < 2; ++kt) {
        bf16x8 wa, wb;
#pragma unroll
        for (int e = 0; e < 8; ++e) {
            int k = kt * 32 + apart * 8 + e;
            wa[e] = (short)f2bf(W2[k * 64 + col]);
            wb[e] = (short)f2bf(W3[k * 64 + col]);
        }
        w2f[kt] = wa;
        w3f[kt] = wb;
    }
    float bb1 = b1[col], bb2 = b2[col], bb3 = b3[col];
    float c = (dtp[0] / (float)REPS) / dxp[0];

    // ---- per-thread w_enc regs + full |w|^2 ----
    int g = t & 3, r = t >> 2;
    const float4* w4p = (const float4*)w_enc;
    float4 w4[4];
#pragma unroll
    for (int j = 0; j < 4; ++j) w4[j] = w4p[g * 4 + j];
    float w2sum = 0.f;
#pragma unroll
    for (int j = 0; j < 4; ++j)
        w2sum += w4[j].x * w4[j].x + w4[j].y * w4[j].y + w4[j].z * w4[j].z + w4[j].w * w4[j].w;
    w2sum += __shfl_xor(w2sum, 1);
    w2sum += __shfl_xor(w2sum, 2);

    // ---- load z tile (row r, cols g*16..g*16+15) ----
    {
        int gr = iclamp(n0 - 3 + r, 0, NN - 1);
        float4* zrow = (float4*)&zt[r * ZP + g * 16];
        if (FIRST) {
            float u = zin[(long)b * NN + gr];
#pragma unroll
            for (int j = 0; j < 4; ++j) {
                float4 o;
                o.x = u * w4[j].x; o.y = u * w4[j].y;
                o.z = u * w4[j].z; o.w = u * w4[j].w;
                zrow[j] = o;
            }
            int n = n0 + r - 3;
            if (g == 0 && r >= 3 && r < 3 + R_OUT && n < NN)
                out[(long)b * NSTEPS * NN + n] = u * (w2sum / (w2sum + 1e-8f));
        } else {
            const float4* zp = (const float4*)(zin + ((long)b * NN + gr) * 64 + g * 16);
#pragma unroll
            for (int j = 0; j < 4; ++j) zrow[j] = zp[j];
        }
    }
    __syncthreads();

    // ---- 3 ghost-boundary sub-steps, z resident in LDS ----
    for (int rep = 0; rep < REPS; ++rep) {
        // build sym features for interface row j=r (global interface i = n0-3+j)
        {
            int j = r;
            int ll = iclamp(iclamp(n0 - 4 + j, 0, NN - 1) - (n0 - 3), 0, TROWS - 1);
            int lr = iclamp(iclamp(n0 - 3 + j, 0, NN - 1) - (n0 - 3), 0, TROWS - 1);
            const float4* zl = (const float4*)&zt[ll * ZP + g * 16];
            const float4* zr = (const float4*)&zt[lr * ZP + g * 16];
            union { unsigned short s[16]; int4 v[2]; } vs, va;
#pragma unroll
            for (int jj = 0; jj < 4; ++jj) {
                float4 a = zl[jj], cc = zr[jj];
                vs.s[jj * 4 + 0] = f2bf(a.x + cc.x);
                vs.s[jj * 4 + 1] = f2bf(a.y + cc.y);
                vs.s[jj * 4 + 2] = f2bf(a.z + cc.z);
                vs.s[jj * 4 + 3] = f2bf(a.w + cc.w);
                va.s[jj * 4 + 0] = f2bf(fabsf(a.x - cc.x));
                va.s[jj * 4 + 1] = f2bf(fabsf(a.y - cc.y));
                va.s[jj * 4 + 2] = f2bf(fabsf(a.z - cc.z));
                va.s[jj * 4 + 3] = f2bf(fabsf(a.w - cc.w));
            }
            int4* xs = (int4*)&Xs[j * XP + g * 16];
            int4* xa = (int4*)&Xs[j * XP + 64 + g * 16];
            xs[0] = vs.v[0]; xs[1] = vs.v[1];
            xa[0] = va.v[0]; xa[1] = va.v[1];
        }
        __syncthreads();

        // layer 1: 64 rows x k128 -> this wave's 16 cols
#pragma unroll
        for (int rt = 0; rt < 4; ++rt) {
            f32x4 acc = (f32x4){0.f, 0.f, 0.f, 0.f};
#pragma unroll
            for (int kt = 0; kt < 4; ++kt) {
                bf16x8 a = *(const bf16x8*)&Xs[(rt * 16 + arow) * XP + kt * 32 + apart * 8];
                acc = __builtin_amdgcn_mfma_f32_16x16x32_bf16(a, w1f[kt], acc, 0, 0, 0);
            }
#pragma unroll
            for (int rr = 0; rr < 4; ++rr) {
                float h = gelu_fast(acc[rr] + bb1);
                H1s[(rt * 16 + apart * 4 + rr) * HP + col] = f2bf(h);
            }
        }
        __syncthreads();

        // layer 2
#pragma unroll
        for (int rt = 0; rt < 4; ++rt) {
            f32x4 acc = (f32x4){0.f, 0.f, 0.f, 0.f};
#pragma unroll
            for (int kt = 0; kt < 2; ++kt) {
                bf16x8 a = *(const bf16x8*)&H1s[(rt * 16 + arow) * HP + kt * 32 + apart * 8];
                acc = __builtin_amdgcn_mfma_f32_16x16x32_bf16(a, w2f[kt], acc, 0, 0, 0);
            }
#pragma unroll
            for (int rr = 0; rr < 4; ++rr) {
                float h = gelu_fast(acc[rr] + bb2);
                H2s[(rt * 16 + apart * 4 + rr) * HP + col] = f2bf(h);
            }
        }
        __syncthreads();

        // layer 3 + tanh*0.25 -> flux (overlays Xs)
#pragma unroll
        for (int rt = 0; rt < 4; ++rt) {
            f32x4 acc = (f32x4){0.f, 0.f, 0.f, 0.f};
#pragma unroll
            for (int kt = 0; kt < 2; ++kt) {
                bf16x8 a = *(const bf16x8*)&H2s[(rt * 16 + arow) * HP + kt * 32 + apart * 8];
                acc = __builtin_amdgcn_mfma_f32_16x16x32_bf16(a, w3f[kt], acc, 0, 0, 0);
            }
#pragma unroll
            for (int rr = 0; rr < 4; ++rr) {
                float f = tanh_fast(acc[rr] + bb3) * 0.25f;
                fluxS[(rt * 16 + apart * 4 + rr) * FP + col] = f;
            }
        }
        __syncthreads();

        // update z tile rows l in [rep+1, TROWS-1-rep)
        {
            int l = r;
            if (l >= rep + 1 && l < TROWS - 1 - rep) {
                float4* zrow = (float4*)&zt[l * ZP + g * 16];
                const float4* fhi = (const float4*)&fluxS[(l + 1) * FP + g * 16];
                const float4* flo = (const float4*)&fluxS[l * FP + g * 16];
#pragma unroll
                for (int j = 0; j < 4; ++j) {
                    float4 zv = zrow[j];
                    float4 h = fhi[j], lo = flo[j];
                    zv.x -= c * (h.x - lo.x);
                    zv.y -= c * (h.y - lo.y);
                    zv.z -= c * (h.z - lo.z);
                    zv.w -= c * (h.w - lo.w);
                    zrow[j] = zv;
                }
            }
        }
        __syncthreads();
    }

    // ---- decode + optional z writeback (owned rows only) ----
    {
        int l = r;
        int n = n0 + l - 3;
        if (l >= 3 && l < 3 + R_OUT && n < NN) {
            float4 zv[4];
            float dot = 0.f;
            const float4* zrow = (const float4*)&zt[l * ZP + g * 16];
#pragma unroll
            for (int j = 0; j < 4; ++j) {
                zv[j] = zrow[j];
                dot += zv[j].x * w4[j].x + zv[j].y * w4[j].y
                     + zv[j].z * w4[j].z + zv[j].w * w4[j].w;
            }
            dot += __shfl_xor(dot, 1);
            dot += __shfl_xor(dot, 2);
            if (g == 0)
                out[((long)b * NSTEPS + step) * NN + n] = dot / (w2sum + 1e-8f);
            if (WRITE_Z) {
                float4* zo = (float4*)(zout + ((long)b * NN + n) * 64 + g * 16);
#pragma unroll
                for (int j = 0; j < 4; ++j) zo[j] = zv[j];
            }
        }
    }
}

extern "C" void kernel_launch(void* const* d_in, const int* in_sizes, int n_in,
                              void* d_out, int out_size, void* d_ws, size_t ws_size,
                              hipStream_t stream) {
    const float* u0 = (const float*)d_in[0];
    const float* w_enc = (const float*)d_in[1];
    const float* W1 = (const float*)d_in[2];
    const float* b1 = (const float*)d_in[3];
    const float* W2 = (const float*)d_in[4];
    const float* b2 = (const float*)d_in[5];
    const float* W3 = (const float*)d_in[6];
    const float* b3 = (const float*)d_in[7];
    const float* dt = (const float*)d_in[8];
    const float* dx = (const float*)d_in[9];
    float* out = (float*)d_out;

    float* z0 = (float*)d_ws;
    float* z1 = z0 + (size_t)NB * NN * LAT;

    dim3 grid(CHUNKS, NB);
    step_kernel<true, true><<<grid, 256, 0, stream>>>(
        u0, z0, out, 1, w_enc, W1, b1, W2, b2, W3, b3, dt, dx);
    step_kernel<false, true><<<grid, 256, 0, stream>>>(
        z0, z1, out, 2, w_enc, W1, b1, W2, b2, W3, b3, dt, dx);
    step_kernel<false, false><<<grid, 256, 0, stream>>>(
        z1, z0, out, 3, w_enc, W1, b1, W2, b2, W3, b3, dt, dx);
}

// Round 4
// 102.509 us; speedup vs baseline: 2.8830x; 1.3263x over previous
//
#include <hip/hip_runtime.h>

#define NB 8
#define NN 8192
#define LAT 64
#define NSTEPS 4
#define REPS 3

#define R_OUT 58            // output z rows per block
#define TROWS 64            // tile rows = R_OUT + 6 (halo 3 each side)
#define CHUNKS 142          // ceil(8192/58)
#define ZP 68               // transient z tile pitch (f32) -> 272B rows
#define XP 136              // X pitch (bf16) -> 272B rows
#define HP 72               // H pitch (bf16) -> 144B rows
#define FP 68               // flux pitch (f32), overlays Xs

typedef __attribute__((ext_vector_type(8))) short bf16x8;
typedef __attribute__((ext_vector_type(4))) float f32x4;

__device__ __forceinline__ unsigned short f2bf(float f) {
    union { float f; unsigned u; } v; v.f = f;
    unsigned r = v.u + 0x7FFFu + ((v.u >> 16) & 1u);  // RNE
    return (unsigned short)(r >> 16);
}

// tanh(x) = 1 - 2*rcp(exp(2x)+1)
__device__ __forceinline__ float tanh_fast(float x) {
    return 1.0f - 2.0f * __builtin_amdgcn_rcpf(__expf(2.0f * x) + 1.0f);
}

// sigmoid-GELU: x * sigmoid(1.702 x)  (max abs err ~0.014, typical <0.008)
__device__ __forceinline__ float gelu_fast(float x) {
    return x * __builtin_amdgcn_rcpf(1.0f + __expf(-1.702f * x));
}

__device__ __forceinline__ int iclamp(int v, int lo, int hi) {
    return v < lo ? lo : (v > hi ? hi : v);
}

// H bank-conflict swizzle: permute 8-col blocks by row bits [2:4]
__device__ __forceinline__ int hswz(int row, int col) {
    return row * HP + (col ^ (((row >> 2) & 7) << 3));
}

template<bool FIRST, bool WRITE_Z>
__global__ __launch_bounds__(256, 4)
void step_kernel(const float* __restrict__ zin,   // u0 when FIRST
                 float* __restrict__ zout,
                 float* __restrict__ out,
                 int step,
                 const float* __restrict__ w_enc,
                 const float* __restrict__ W1, const float* __restrict__ b1,
                 const float* __restrict__ W2, const float* __restrict__ b2,
                 const float* __restrict__ W3, const float* __restrict__ b3,
                 const float* __restrict__ dtp, const float* __restrict__ dxp) {
    __shared__ unsigned short Xs[TROWS * XP];            // 17408 B; flux overlays
    __shared__ __align__(16) unsigned short Hbuf[2 * TROWS * HP];  // 18432 B
    unsigned short* H1s = Hbuf;
    unsigned short* H2s = Hbuf + TROWS * HP;
    float* ztO = (float*)Hbuf;                           // transient z tile (17408 B)
    float* fluxS = (float*)Xs;                           // [TROWS][FP]

    int t = threadIdx.x;
    int chunk = blockIdx.x;
    int b = blockIdx.y;
    int n0 = chunk * R_OUT;

    int lane = t & 63;
    int wv = t >> 6;           // wave id == output column tile
    int arow = lane & 15;
    int apart = lane >> 4;
    int col = wv * 16 + arow;  // this lane's MLP output column

    // ---- per-wave weight fragments (registers, L2-cached gather) ----
    bf16x8 w1f[4], w2f[2], w3f[2];
#pragma unroll
    for (int kt = 0; kt < 4; ++kt) {
        bf16x8 w;
#pragma unroll
        for (int e = 0; e < 8; ++e) {
            int k = kt * 32 + apart * 8 + e;
            w[e] = (short)f2bf(W1[k * 64 + col]);
        }
        w1f[kt] = w;
    }
#pragma unroll
    for (int kt = 0; kt < 2; ++kt) {
        bf16x8 wa, wb;
#pragma unroll
        for (int e = 0; e < 8; ++e) {
            int k = kt * 32 + apart * 8 + e;
            wa[e] = (short)f2bf(W2[k * 64 + col]);
            wb[e] = (short)f2bf(W3[k * 64 + col]);
        }
        w2f[kt] = wa;
        w3f[kt] = wb;
    }
    float bb1 = b1[col], bb2 = b2[col], bb3 = b3[col];
    float c = (dtp[0] / (float)REPS) * __builtin_amdgcn_rcpf(dxp[0]);

    // ---- per-thread w_enc regs + full |w|^2 ----
    int g = t & 3, r = t >> 2;   // this thread owns tile row r, cols [16g,16g+16)
    const float4* w4p = (const float4*)w_enc;
    float4 w4[4];
#pragma unroll
    for (int j = 0; j < 4; ++j) w4[j] = w4p[g * 4 + j];
    float w2sum = 0.f;
#pragma unroll
    for (int j = 0; j < 4; ++j)
        w2sum += w4[j].x * w4[j].x + w4[j].y * w4[j].y + w4[j].z * w4[j].z + w4[j].w * w4[j].w;
    w2sum += __shfl_xor(w2sum, 1);
    w2sum += __shfl_xor(w2sum, 2);

    // ---- clamped source rows for X build (constant per thread) ----
    int iGl = iclamp(n0 - 4 + r, 0, NN - 1);
    int iGr = iclamp(n0 - 3 + r, 0, NN - 1);
    int jl = iclamp(iGl - (n0 - 3), 0, TROWS - 1);
    int jr = iclamp(iGr - (n0 - 3), 0, TROWS - 1);

    // ---- load own z row slice into registers ----
    float4 z[4];
    {
        int gr = iclamp(n0 - 3 + r, 0, NN - 1);
        if (FIRST) {
            float u = zin[(long)b * NN + gr];
#pragma unroll
            for (int j = 0; j < 4; ++j) {
                z[j].x = u * w4[j].x; z[j].y = u * w4[j].y;
                z[j].z = u * w4[j].z; z[j].w = u * w4[j].w;
            }
            int n = n0 + r - 3;
            if (g == 0 && r >= 3 && r < 3 + R_OUT && n < NN)
                out[(long)b * NSTEPS * NN + n] = u * (w2sum / (w2sum + 1e-8f));
        } else {
            const float4* zp = (const float4*)(zin + ((long)b * NN + gr) * 64 + g * 16);
#pragma unroll
            for (int j = 0; j < 4; ++j) z[j] = zp[j];
        }
    }

    // ---- 3 ghost-boundary sub-steps ----
    for (int rep = 0; rep < REPS; ++rep) {
        // phase A: materialize z tile into LDS (aliases H1/H2 region)
        {
            float4* zrow = (float4*)&ztO[r * ZP + g * 16];
#pragma unroll
            for (int j = 0; j < 4; ++j) zrow[j] = z[j];
        }
        __syncthreads();

        // phase B: build sym features X[r][0:64]=zl+zr, X[r][64:128]=|zl-zr|
        {
            float4 zlv[4], zrv[4];
            const float4* zl4 = (const float4*)&ztO[jl * ZP + g * 16];
#pragma unroll
            for (int j = 0; j < 4; ++j) zlv[j] = zl4[j];
            if (jr == r) {
#pragma unroll
                for (int j = 0; j < 4; ++j) zrv[j] = z[j];
            } else {
                const float4* zr4 = (const float4*)&ztO[jr * ZP + g * 16];
#pragma unroll
                for (int j = 0; j < 4; ++j) zrv[j] = zr4[j];
            }
            union { unsigned short s[16]; int4 v[2]; } vs, va;
#pragma unroll
            for (int jj = 0; jj < 4; ++jj) {
                float4 a = zlv[jj], cc = zrv[jj];
                vs.s[jj * 4 + 0] = f2bf(a.x + cc.x);
                vs.s[jj * 4 + 1] = f2bf(a.y + cc.y);
                vs.s[jj * 4 + 2] = f2bf(a.z + cc.z);
                vs.s[jj * 4 + 3] = f2bf(a.w + cc.w);
                va.s[jj * 4 + 0] = f2bf(fabsf(a.x - cc.x));
                va.s[jj * 4 + 1] = f2bf(fabsf(a.y - cc.y));
                va.s[jj * 4 + 2] = f2bf(fabsf(a.z - cc.z));
                va.s[jj * 4 + 3] = f2bf(fabsf(a.w - cc.w));
            }
            int4* xs = (int4*)&Xs[r * XP + g * 16];
            int4* xa = (int4*)&Xs[r * XP + 64 + g * 16];
            xs[0] = vs.v[0]; xs[1] = vs.v[1];
            xa[0] = va.v[0]; xa[1] = va.v[1];
        }
        __syncthreads();

        // layer 1: 64 rows x k128 -> this wave's 16 cols
#pragma unroll
        for (int rt = 0; rt < 4; ++rt) {
            f32x4 acc = (f32x4){0.f, 0.f, 0.f, 0.f};
#pragma unroll
            for (int kt = 0; kt < 4; ++kt) {
                bf16x8 a = *(const bf16x8*)&Xs[(rt * 16 + arow) * XP + kt * 32 + apart * 8];
                acc = __builtin_amdgcn_mfma_f32_16x16x32_bf16(a, w1f[kt], acc, 0, 0, 0);
            }
#pragma unroll
            for (int rr = 0; rr < 4; ++rr) {
                float h = gelu_fast(acc[rr] + bb1);
                H1s[hswz(rt * 16 + apart * 4 + rr, col)] = f2bf(h);
            }
        }
        __syncthreads();

        // layer 2
#pragma unroll
        for (int rt = 0; rt < 4; ++rt) {
            f32x4 acc = (f32x4){0.f, 0.f, 0.f, 0.f};
#pragma unroll
            for (int kt = 0; kt < 2; ++kt) {
                bf16x8 a = *(const bf16x8*)&H1s[hswz(rt * 16 + arow, kt * 32 + apart * 8)];
                acc = __builtin_amdgcn_mfma_f32_16x16x32_bf16(a, w2f[kt], acc, 0, 0, 0);
            }
#pragma unroll
            for (int rr = 0; rr < 4; ++rr) {
                float h = gelu_fast(acc[rr] + bb2);
                H2s[hswz(rt * 16 + apart * 4 + rr, col)] = f2bf(h);
            }
        }
        __syncthreads();

        // layer 3 + tanh*0.25 -> flux (overlays Xs)
#pragma unroll
        for (int rt = 0; rt < 4; ++rt) {
            f32x4 acc = (f32x4){0.f, 0.f, 0.f, 0.f};
#pragma unroll
            for (int kt = 0; kt < 2; ++kt) {
                bf16x8 a = *(const bf16x8*)&H2s[hswz(rt * 16 + arow, kt * 32 + apart * 8)];
                acc = __builtin_amdgcn_mfma_f32_16x16x32_bf16(a, w3f[kt], acc, 0, 0, 0);
            }
#pragma unroll
            for (int rr = 0; rr < 4; ++rr) {
                float f = tanh_fast(acc[rr] + bb3) * 0.25f;
                fluxS[(rt * 16 + apart * 4 + rr) * FP + col] = f;
            }
        }
        __syncthreads();

        // update own z (registers) from flux rows r, r+1
        if (r >= rep + 1 && r < TROWS - 1 - rep) {
            const float4* fhi = (const float4*)&fluxS[(r + 1) * FP + g * 16];
            const float4* flo = (const float4*)&fluxS[r * FP + g * 16];
#pragma unroll
            for (int j = 0; j < 4; ++j) {
                float4 h = fhi[j], lo = flo[j];
                z[j].x -= c * (h.x - lo.x);
                z[j].y -= c * (h.y - lo.y);
                z[j].z -= c * (h.z - lo.z);
                z[j].w -= c * (h.w - lo.w);
            }
        }
        // no barrier needed here: update reads Xs-region, next phase A writes H-region
    }

    // ---- decode + optional z writeback (owned rows only, all in registers) ----
    {
        int n = n0 + r - 3;
        if (r >= 3 && r < 3 + R_OUT && n < NN) {
            float dot = 0.f;
#pragma unroll
            for (int j = 0; j < 4; ++j) {
                dot += z[j].x * w4[j].x + z[j].y * w4[j].y
                     + z[j].z * w4[j].z + z[j].w * w4[j].w;
            }
            dot += __shfl_xor(dot, 1);
            dot += __shfl_xor(dot, 2);
            if (g == 0)
                out[((long)b * NSTEPS + step) * NN + n] = dot / (w2sum + 1e-8f);
            if (WRITE_Z) {
                float4* zo = (float4*)(zout + ((long)b * NN + n) * 64 + g * 16);
#pragma unroll
                for (int j = 0; j < 4; ++j) zo[j] = z[j];
            }
        }
    }
}

extern "C" void kernel_launch(void* const* d_in, const int* in_sizes, int n_in,
                              void* d_out, int out_size, void* d_ws, size_t ws_size,
                              hipStream_t stream) {
    const float* u0 = (const float*)d_in[0];
    const float* w_enc = (const float*)d_in[1];
    const float* W1 = (const float*)d_in[2];
    const float* b1 = (const float*)d_in[3];
    const float* W2 = (const float*)d_in[4];
    const float* b2 = (const float*)d_in[5];
    const float* W3 = (const float*)d_in[6];
    const float* b3 = (const float*)d_in[7];
    const float* dt = (const float*)d_in[8];
    const float* dx = (const float*)d_in[9];
    float* out = (float*)d_out;

    float* z0 = (float*)d_ws;
    float* z1 = z0 + (size_t)NB * NN * LAT;

    dim3 grid(CHUNKS, NB);
    step_kernel<true, true><<<grid, 256, 0, stream>>>(
        u0, z0, out, 1, w_enc, W1, b1, W2, b2, W3, b3, dt, dx);
    step_kernel<false, true><<<grid, 256, 0, stream>>>(
        z0, z1, out, 2, w_enc, W1, b1, W2, b2, W3, b3, dt, dx);
    step_kernel<false, false><<<grid, 256, 0, stream>>>(
        z1, z0, out, 3, w_enc, W1, b1, W2, b2, W3, b3, dt, dx);
}